// Round 1
// baseline (582.993 us; speedup 1.0000x reference)
//
#include <hip/hip_runtime.h>

typedef __bf16 bf16x8 __attribute__((ext_vector_type(8)));
typedef float f32x4 __attribute__((ext_vector_type(4)));

#define DEVI static __device__ __forceinline__

DEVI unsigned short f2bf(float f){
  unsigned int x = __builtin_bit_cast(unsigned int, f);
  x = (x + 0x7fffu + ((x >> 16) & 1u)) >> 16;
  return (unsigned short)x;
}
DEVI unsigned int packbf2(float a, float b){
  return (unsigned int)f2bf(a) | ((unsigned int)f2bf(b) << 16);
}
DEVI float bflo(unsigned int u){ return __builtin_bit_cast(float, u << 16); }
DEVI float bfhi(unsigned int u){ return __builtin_bit_cast(float, u & 0xffff0000u); }

__global__ void k_zero(int* __restrict__ p, int n){
  int i = blockIdx.x*256 + threadIdx.x;
  if (i < n) p[i] = 0;
}

__global__ void k_count(const int* __restrict__ dst, int* __restrict__ cnt, int E){
  int e = blockIdx.x*256 + threadIdx.x;
  if (e < E) atomicAdd(&cnt[dst[e]], 1);
}

__global__ void k_scan1(const int* __restrict__ cnt, int* __restrict__ rp,
                        int* __restrict__ partials, int n){
  __shared__ int sh[256];
  int t = threadIdx.x;
  int base = blockIdx.x*1024 + t*4;
  int v0=0,v1=0,v2=0,v3=0;
  if (base+0 < n) v0 = cnt[base+0];
  if (base+1 < n) v1 = cnt[base+1];
  if (base+2 < n) v2 = cnt[base+2];
  if (base+3 < n) v3 = cnt[base+3];
  int s = v0+v1+v2+v3;
  sh[t] = s; __syncthreads();
  for (int off=1; off<256; off<<=1){
    int x = (t>=off) ? sh[t-off] : 0;
    __syncthreads();
    sh[t] += x;
    __syncthreads();
  }
  if (t==255) partials[blockIdx.x] = sh[255];
  int run = sh[t]-s;
  if (base+0 < n) rp[base+0] = run; run += v0;
  if (base+1 < n) rp[base+1] = run; run += v1;
  if (base+2 < n) rp[base+2] = run; run += v2;
  if (base+3 < n) rp[base+3] = run;
}

__global__ void k_scan2(int* __restrict__ partials, int P){
  __shared__ int sh[256];
  int t = threadIdx.x;
  int v = (t<P) ? partials[t] : 0;
  sh[t] = v; __syncthreads();
  for (int off=1; off<256; off<<=1){
    int x = (t>=off) ? sh[t-off] : 0;
    __syncthreads();
    sh[t] += x;
    __syncthreads();
  }
  if (t<P) partials[t] = sh[t]-v;
}

__global__ void k_scan3(int* __restrict__ rp, int* __restrict__ cur,
                        const int* __restrict__ partials, int n, int E){
  int i = blockIdx.x*256 + threadIdx.x;
  if (i < n){ int v = rp[i] + partials[i>>10]; rp[i]=v; cur[i]=v; }
  else if (i == n) rp[n] = E;
}

__global__ void k_dinv(const int* __restrict__ cnt, float* __restrict__ dinv, int n){
  int i = blockIdx.x*256 + threadIdx.x;
  if (i<n) dinv[i] = rsqrtf((float)(cnt[i]+1));
}

__global__ void k_fill(const int* __restrict__ src, const int* __restrict__ dst,
                       int* __restrict__ cur, int* __restrict__ csr, int E){
  int e = blockIdx.x*256 + threadIdx.x;
  if (e<E){
    int d = dst[e];
    int p = atomicAdd(&cur[d], 1);
    csr[p] = src[e];
  }
}

__global__ void k_cvt(const float2* __restrict__ x, unsigned int* __restrict__ xb, int n2){
  int i = blockIdx.x*256 + threadIdx.x;
  if (i<n2){ float2 v = x[i]; xb[i] = packbf2(v.x, v.y); }
}

// Pack row-major fp32 W[K][N] into MFMA B-fragment order:
// frag (ks, cf), lane l, elem j  <-  W[ks*32 + (l>>4)*8 + j][cf*16 + (l&15)]
__global__ void k_pack(const float* __restrict__ W, unsigned short* __restrict__ Wp,
                       int N, int KS, int NF){
  int idx = blockIdx.x*256 + threadIdx.x;
  if (idx >= KS*NF*64) return;
  int l = idx & 63;
  int frag = idx >> 6;
  int cf = frag % NF;
  int ks = frag / NF;
  int kbase = ks*32 + (l>>4)*8;
  int col = cf*16 + (l&15);
  unsigned short* dp = Wp + (size_t)idx*8;
  for (int j=0;j<8;j++) dp[j] = f2bf(W[(size_t)(kbase+j)*N + col]);
}

// One wave per node, lane l owns features {2l, 2l+1} (bf16 pair = 4B).
__global__ __launch_bounds__(256) void k_agg1(
    const unsigned int* __restrict__ xb, const int* __restrict__ rp,
    const int* __restrict__ csr, const float* __restrict__ dinv,
    unsigned int* __restrict__ outb, int n){
  int node = blockIdx.x*4 + (threadIdx.x>>6);
  if (node >= n) return;
  int l = threadIdx.x & 63;
  float dn = dinv[node];
  unsigned int u = xb[(size_t)node*64 + l];
  float a0 = dn*bflo(u), a1 = dn*bfhi(u);
  int e = rp[node], end = rp[node+1];
  for (; e<end; ++e){
    int s = csr[e];
    float ds = dinv[s];
    unsigned int v = xb[(size_t)s*64 + l];
    a0 += ds*bflo(v);
    a1 += ds*bfhi(v);
  }
  outb[(size_t)node*64 + l] = packbf2(a0*dn, a1*dn);
}

__global__ __launch_bounds__(256) void k_agg2(
    const unsigned int* __restrict__ tb, const int* __restrict__ rp,
    const int* __restrict__ csr, const float* __restrict__ dinv,
    const float* __restrict__ b2, float* __restrict__ out, int n){
  int node = blockIdx.x*4 + (threadIdx.x>>6);
  if (node >= n) return;
  int l = threadIdx.x & 63;
  float dn = dinv[node];
  unsigned int u = tb[(size_t)node*64 + l];
  float a0 = dn*bflo(u), a1 = dn*bfhi(u);
  int e = rp[node], end = rp[node+1];
  for (; e<end; ++e){
    int s = csr[e];
    float ds = dinv[s];
    unsigned int v = tb[(size_t)s*64 + l];
    a0 += ds*bflo(v);
    a1 += ds*bfhi(v);
  }
  float2 r;
  r.x = a0*dn + b2[2*l];
  r.y = a1*dn + b2[2*l+1];
  *(float2*)(out + (size_t)node*128 + 2*l) = r;
}

// C[M][N] (bf16) = A[M][K] (bf16, row-major) @ Wp (packed frags) [+bias, relu]
// 4 waves/block; wave computes 64x64 via 4x4 grid of 16x16x32 MFMA fragments.
template<int K, int N, bool BIASRELU>
__global__ __launch_bounds__(256) void k_gemm(
    const unsigned short* __restrict__ A, const unsigned short* __restrict__ Wp,
    const float* __restrict__ bias, unsigned short* __restrict__ C, int M){
  constexpr int KS = K/32;
  constexpr int NF = N/16;
  constexpr int NWC = N/64;       // waves along cols
  constexpr int NWR = 4/NWC;      // waves along rows
  constexpr int BM = 64*NWR;
  int l = threadIdx.x & 63;
  int w = threadIdx.x >> 6;
  int wr = w / NWC, wc = w % NWC;
  int r0 = blockIdx.x*BM + wr*64;
  int c0 = wc*64;
  int lr = l & 15, lg = l >> 4;
  f32x4 acc[4][4];
  #pragma unroll
  for (int i=0;i<4;i++)
    #pragma unroll
    for (int j=0;j<4;j++)
      acc[i][j] = f32x4{0.f,0.f,0.f,0.f};
  for (int ks=0; ks<KS; ++ks){
    bf16x8 a[4], b[4];
    #pragma unroll
    for (int ar=0;ar<4;ar++){
      int row = r0 + ar*16 + lr;
      if (row > M-1) row = M-1;
      const uint4* p = (const uint4*)(A + (size_t)row*K + ks*32 + lg*8);
      union { uint4 u; bf16x8 v; } t; t.u = *p; a[ar] = t.v;
    }
    #pragma unroll
    for (int cb=0;cb<4;cb++){
      int cf = (c0>>4) + cb;
      const uint4* p = (const uint4*)(Wp + ((size_t)(ks*NF + cf)*64 + l)*8);
      union { uint4 u; bf16x8 v; } t; t.u = *p; b[cb] = t.v;
    }
    #pragma unroll
    for (int ar=0;ar<4;ar++)
      #pragma unroll
      for (int cb=0;cb<4;cb++)
        acc[ar][cb] = __builtin_amdgcn_mfma_f32_16x16x32_bf16(a[ar], b[cb], acc[ar][cb], 0, 0, 0);
  }
  #pragma unroll
  for (int ar=0;ar<4;ar++){
    #pragma unroll
    for (int i=0;i<4;i++){
      int row = r0 + ar*16 + lg*4 + i;
      if (row < M){
        #pragma unroll
        for (int cb=0;cb<4;cb++){
          int col = c0 + cb*16 + lr;
          float v = acc[ar][cb][i];
          if constexpr (BIASRELU){ v += bias[col]; v = fmaxf(v, 0.f); }
          C[(size_t)row*N + col] = f2bf(v);
        }
      }
    }
  }
}

extern "C" void kernel_launch(void* const* d_in, const int* in_sizes, int n_in,
                              void* d_out, int out_size, void* d_ws, size_t ws_size,
                              hipStream_t stream){
  const float* x  = (const float*)d_in[0];
  const int*   ei = (const int*)d_in[1];
  const float* W1 = (const float*)d_in[2];
  const float* b1 = (const float*)d_in[3];
  const float* W2 = (const float*)d_in[4];
  const float* b2 = (const float*)d_in[5];
  const int IN_F = 128, H_F = 256, OUT_F = 128;
  int n = in_sizes[0] / IN_F;      // 100000
  int E = in_sizes[1] / 2;         // 1600000
  const int* srcI = ei;
  const int* dstI = ei + E;

  char* ws = (char*)d_ws;
  size_t off = 0;
  auto alloc = [&](size_t bytes)->char*{
    char* p = ws + off; off += (bytes + 255) & ~(size_t)255; return p;
  };
  int*   cnt   = (int*)  alloc((size_t)n*4);
  int*   rp    = (int*)  alloc(((size_t)n+1)*4);
  int*   cur   = (int*)  alloc((size_t)n*4);
  float* dinv  = (float*)alloc((size_t)n*4);
  int*   parts = (int*)  alloc(1024);
  unsigned short* W1p = (unsigned short*)alloc((size_t)IN_F*H_F*2);
  unsigned short* W2p = (unsigned short*)alloc((size_t)H_F*OUT_F*2);
  int*   csr   = (int*)  alloc((size_t)E*4);
  unsigned int* xb = (unsigned int*)alloc((size_t)n*(IN_F/2)*4);  // reused as T after GEMM1
  unsigned int* AX = (unsigned int*)alloc((size_t)n*(IN_F/2)*4);
  unsigned short* H1 = (unsigned short*)alloc((size_t)n*H_F*2);

  int g256n = (n+255)/256;
  int gE = (E+255)/256;
  int P = (n+1023)/1024;

  k_zero<<<g256n,256,0,stream>>>(cnt, n);
  k_count<<<gE,256,0,stream>>>(dstI, cnt, E);
  k_scan1<<<P,256,0,stream>>>(cnt, rp, parts, n);
  k_scan2<<<1,256,0,stream>>>(parts, P);
  k_scan3<<<(n+256)/256,256,0,stream>>>(rp, cur, parts, n, E);
  k_dinv<<<g256n,256,0,stream>>>(cnt, dinv, n);
  k_fill<<<gE,256,0,stream>>>(srcI, dstI, cur, csr, E);
  k_cvt<<<((n*(IN_F/2))+255)/256,256,0,stream>>>((const float2*)x, xb, n*(IN_F/2));
  k_pack<<<16,256,0,stream>>>(W1, W1p, H_F, IN_F/32, H_F/16);
  k_pack<<<16,256,0,stream>>>(W2, W2p, OUT_F, H_F/32, OUT_F/16);
  k_agg1<<<(n+3)/4,256,0,stream>>>(xb, rp, csr, dinv, AX, n);
  k_gemm<128,256,true><<<(n+63)/64,256,0,stream>>>((const unsigned short*)AX, W1p, b1, H1, n);
  unsigned int* T = xb;
  k_gemm<256,128,false><<<(n+127)/128,256,0,stream>>>(H1, W2p, nullptr, (unsigned short*)T, n);
  k_agg2<<<(n+3)/4,256,0,stream>>>(T, rp, csr, dinv, b2, (float*)d_out, n);
}

// Round 2
// 413.065 us; speedup vs baseline: 1.4114x; 1.4114x over previous
//
#include <hip/hip_runtime.h>

typedef __bf16 bf16x8 __attribute__((ext_vector_type(8)));
typedef float f32x4 __attribute__((ext_vector_type(4)));

#define DEVI static __device__ __forceinline__

DEVI unsigned short f2bf(float f){
  unsigned int x = __builtin_bit_cast(unsigned int, f);
  x = (x + 0x7fffu + ((x >> 16) & 1u)) >> 16;
  return (unsigned short)x;
}
DEVI unsigned int packbf2(float a, float b){
  return (unsigned int)f2bf(a) | ((unsigned int)f2bf(b) << 16);
}
DEVI float bflo(unsigned int u){ return __builtin_bit_cast(float, u << 16); }
DEVI float bfhi(unsigned int u){ return __builtin_bit_cast(float, u & 0xffff0000u); }

__global__ void k_zero(int* __restrict__ p, int n){
  int i = blockIdx.x*256 + threadIdx.x;
  if (i < n) p[i] = 0;
}

__global__ void k_count(const int* __restrict__ dst, int* __restrict__ cnt, int E){
  int e = blockIdx.x*256 + threadIdx.x;
  if (e < E) atomicAdd(&cnt[dst[e]], 1);
}

__global__ void k_scan1(const int* __restrict__ cnt, int* __restrict__ rp,
                        int* __restrict__ partials, int n){
  __shared__ int sh[256];
  int t = threadIdx.x;
  int base = blockIdx.x*1024 + t*4;
  int v0=0,v1=0,v2=0,v3=0;
  if (base+0 < n) v0 = cnt[base+0];
  if (base+1 < n) v1 = cnt[base+1];
  if (base+2 < n) v2 = cnt[base+2];
  if (base+3 < n) v3 = cnt[base+3];
  int s = v0+v1+v2+v3;
  sh[t] = s; __syncthreads();
  for (int off=1; off<256; off<<=1){
    int x = (t>=off) ? sh[t-off] : 0;
    __syncthreads();
    sh[t] += x;
    __syncthreads();
  }
  if (t==255) partials[blockIdx.x] = sh[255];
  int run = sh[t]-s;
  if (base+0 < n) rp[base+0] = run; run += v0;
  if (base+1 < n) rp[base+1] = run; run += v1;
  if (base+2 < n) rp[base+2] = run; run += v2;
  if (base+3 < n) rp[base+3] = run;
}

__global__ void k_scan2(int* __restrict__ partials, int P){
  __shared__ int sh[256];
  int t = threadIdx.x;
  int v = (t<P) ? partials[t] : 0;
  sh[t] = v; __syncthreads();
  for (int off=1; off<256; off<<=1){
    int x = (t>=off) ? sh[t-off] : 0;
    __syncthreads();
    sh[t] += x;
    __syncthreads();
  }
  if (t<P) partials[t] = sh[t]-v;
}

__global__ void k_scan3(int* __restrict__ rp, int* __restrict__ cur,
                        const int* __restrict__ partials, int n, int E){
  int i = blockIdx.x*256 + threadIdx.x;
  if (i < n){ int v = rp[i] + partials[i>>10]; rp[i]=v; cur[i]=v; }
  else if (i == n) rp[n] = E;
}

__global__ void k_dinv(const int* __restrict__ cnt, float* __restrict__ dinv, int n){
  int i = blockIdx.x*256 + threadIdx.x;
  if (i<n) dinv[i] = rsqrtf((float)(cnt[i]+1));
}

__global__ void k_fill(const int* __restrict__ src, const int* __restrict__ dst,
                       int* __restrict__ cur, int* __restrict__ csr, int E){
  int e = blockIdx.x*256 + threadIdx.x;
  if (e<E){
    int d = dst[e];
    int p = atomicAdd(&cur[d], 1);
    csr[p] = src[e];
  }
}

// xs[node] = bf16(dinv[node] * x[node])  (pre-scaled rows)
__global__ void k_cvt(const float2* __restrict__ x, const float* __restrict__ dinv,
                      unsigned int* __restrict__ xb, int n2){
  int i = blockIdx.x*256 + threadIdx.x;
  if (i<n2){
    float d = dinv[i>>6];
    float2 v = x[i];
    xb[i] = packbf2(d*v.x, d*v.y);
  }
}

// Pack row-major fp32 W[K][N] into MFMA B-fragment order:
// frag (ks, cf), lane l, elem j  <-  W[ks*32 + (l>>4)*8 + j][cf*16 + (l&15)]
__global__ void k_pack(const float* __restrict__ W, unsigned short* __restrict__ Wp,
                       int N, int KS, int NF){
  int idx = blockIdx.x*256 + threadIdx.x;
  if (idx >= KS*NF*64) return;
  int l = idx & 63;
  int frag = idx >> 6;
  int cf = frag % NF;
  int ks = frag / NF;
  int kbase = ks*32 + (l>>4)*8;
  int col = cf*16 + (l&15);
  unsigned short* dp = Wp + (size_t)idx*8;
  for (int j=0;j<8;j++) dp[j] = f2bf(W[(size_t)(kbase+j)*N + col]);
}

// Aggregate pre-scaled rows: out[d] = dinv[d] * (sum_{s in N(d)} xs[s] + xs[d])
// One wave per node, lane l owns feature pair {2l,2l+1} (4B). 8-wide unrolled
// gather loop for MLP; predicated tail (clamped index, zeroed value).
template<bool FINAL>
__global__ __launch_bounds__(256) void k_agg(
    const unsigned int* __restrict__ xs, const int* __restrict__ rp,
    const int* __restrict__ csr, const float* __restrict__ dinv,
    const float* __restrict__ bias, unsigned int* __restrict__ outb,
    float* __restrict__ outf, int n){
  int node = blockIdx.x*4 + (threadIdx.x>>6);
  if (node >= n) return;
  int l = threadIdx.x & 63;
  float dn = dinv[node];
  unsigned int u = xs[(size_t)node*64 + l];
  float a0 = bflo(u), a1 = bfhi(u);
  int e = rp[node], end = rp[node+1];
  for (int base = e; base < end; base += 8){
    int idx[8];
    unsigned int v[8];
    #pragma unroll
    for (int i=0;i<8;i++){
      int ei = base+i < end-1 ? base+i : end-1;
      idx[i] = csr[ei];
    }
    #pragma unroll
    for (int i=0;i<8;i++)
      v[i] = xs[(size_t)idx[i]*64 + l];
    #pragma unroll
    for (int i=0;i<8;i++){
      if (base+i >= end) v[i] = 0;
      a0 += bflo(v[i]);
      a1 += bfhi(v[i]);
    }
  }
  if constexpr (FINAL){
    float2 r;
    r.x = a0*dn + bias[2*l];
    r.y = a1*dn + bias[2*l+1];
    *(float2*)(outf + (size_t)node*128 + 2*l) = r;
  } else {
    outb[(size_t)node*64 + l] = packbf2(a0*dn, a1*dn);
  }
}

// C[M][N] (bf16) = A[M][K] (bf16, row-major) @ Wp (packed frags)
// [+bias+relu] or [*rowscale] epilogue.
// 4 waves/block; wave computes 64x64 via 4x4 grid of 16x16x32 MFMA fragments.
template<int K, int N, bool BIASRELU, bool ROWSCALE>
__global__ __launch_bounds__(256) void k_gemm(
    const unsigned short* __restrict__ A, const unsigned short* __restrict__ Wp,
    const float* __restrict__ bias, const float* __restrict__ rowscale,
    unsigned short* __restrict__ C, int M){
  constexpr int KS = K/32;
  constexpr int NF = N/16;
  constexpr int NWC = N/64;       // waves along cols
  constexpr int NWR = 4/NWC;      // waves along rows
  constexpr int BM = 64*NWR;
  int l = threadIdx.x & 63;
  int w = threadIdx.x >> 6;
  int wr = w / NWC, wc = w % NWC;
  int r0 = blockIdx.x*BM + wr*64;
  int c0 = wc*64;
  int lr = l & 15, lg = l >> 4;
  f32x4 acc[4][4];
  #pragma unroll
  for (int i=0;i<4;i++)
    #pragma unroll
    for (int j=0;j<4;j++)
      acc[i][j] = f32x4{0.f,0.f,0.f,0.f};
  for (int ks=0; ks<KS; ++ks){
    bf16x8 a[4], b[4];
    #pragma unroll
    for (int ar=0;ar<4;ar++){
      int row = r0 + ar*16 + lr;
      if (row > M-1) row = M-1;
      const uint4* p = (const uint4*)(A + (size_t)row*K + ks*32 + lg*8);
      union { uint4 u; bf16x8 v; } t; t.u = *p; a[ar] = t.v;
    }
    #pragma unroll
    for (int cb=0;cb<4;cb++){
      int cf = (c0>>4) + cb;
      const uint4* p = (const uint4*)(Wp + ((size_t)(ks*NF + cf)*64 + l)*8);
      union { uint4 u; bf16x8 v; } t; t.u = *p; b[cb] = t.v;
    }
    #pragma unroll
    for (int ar=0;ar<4;ar++)
      #pragma unroll
      for (int cb=0;cb<4;cb++)
        acc[ar][cb] = __builtin_amdgcn_mfma_f32_16x16x32_bf16(a[ar], b[cb], acc[ar][cb], 0, 0, 0);
  }
  #pragma unroll
  for (int ar=0;ar<4;ar++){
    #pragma unroll
    for (int i=0;i<4;i++){
      int row = r0 + ar*16 + lg*4 + i;
      if (row < M){
        float rs = 1.f;
        if constexpr (ROWSCALE) rs = rowscale[row];
        #pragma unroll
        for (int cb=0;cb<4;cb++){
          int col = c0 + cb*16 + lr;
          float v = acc[ar][cb][i];
          if constexpr (BIASRELU){ v += bias[col]; v = fmaxf(v, 0.f); }
          if constexpr (ROWSCALE) v *= rs;
          C[(size_t)row*N + col] = f2bf(v);
        }
      }
    }
  }
}

extern "C" void kernel_launch(void* const* d_in, const int* in_sizes, int n_in,
                              void* d_out, int out_size, void* d_ws, size_t ws_size,
                              hipStream_t stream){
  const float* x  = (const float*)d_in[0];
  const int*   ei = (const int*)d_in[1];
  const float* W1 = (const float*)d_in[2];
  const float* b1 = (const float*)d_in[3];
  const float* W2 = (const float*)d_in[4];
  const float* b2 = (const float*)d_in[5];
  const int IN_F = 128, H_F = 256, OUT_F = 128;
  int n = in_sizes[0] / IN_F;      // 100000
  int E = in_sizes[1] / 2;         // 1600000
  const int* srcI = ei;
  const int* dstI = ei + E;

  char* ws = (char*)d_ws;
  size_t off = 0;
  auto alloc = [&](size_t bytes)->char*{
    char* p = ws + off; off += (bytes + 255) & ~(size_t)255; return p;
  };
  int*   cnt   = (int*)  alloc((size_t)n*4);
  int*   rp    = (int*)  alloc(((size_t)n+1)*4);
  int*   cur   = (int*)  alloc((size_t)n*4);
  float* dinv  = (float*)alloc((size_t)n*4);
  int*   parts = (int*)  alloc(1024);
  unsigned short* W1p = (unsigned short*)alloc((size_t)IN_F*H_F*2);
  unsigned short* W2p = (unsigned short*)alloc((size_t)H_F*OUT_F*2);
  int*   csr   = (int*)  alloc((size_t)E*4);
  unsigned int* xb = (unsigned int*)alloc((size_t)n*(IN_F/2)*4);  // reused as T after GEMM1
  unsigned int* AX = (unsigned int*)alloc((size_t)n*(IN_F/2)*4);
  unsigned short* H1 = (unsigned short*)alloc((size_t)n*H_F*2);

  int g256n = (n+255)/256;
  int gE = (E+255)/256;
  int P = (n+1023)/1024;

  k_zero<<<g256n,256,0,stream>>>(cnt, n);
  k_count<<<gE,256,0,stream>>>(dstI, cnt, E);
  k_scan1<<<P,256,0,stream>>>(cnt, rp, parts, n);
  k_scan2<<<1,256,0,stream>>>(parts, P);
  k_scan3<<<(n+256)/256,256,0,stream>>>(rp, cur, parts, n, E);
  k_dinv<<<g256n,256,0,stream>>>(cnt, dinv, n);
  k_fill<<<gE,256,0,stream>>>(srcI, dstI, cur, csr, E);
  k_cvt<<<((n*(IN_F/2))+255)/256,256,0,stream>>>((const float2*)x, dinv, xb, n*(IN_F/2));
  k_pack<<<16,256,0,stream>>>(W1, W1p, H_F, IN_F/32, H_F/16);
  k_pack<<<16,256,0,stream>>>(W2, W2p, OUT_F, H_F/32, OUT_F/16);
  // layer 1: AX = A_hat @ xs ; H1 = relu(AX @ W1 + b1)
  k_agg<false><<<(n+3)/4,256,0,stream>>>(xb, rp, csr, dinv, nullptr, AX, nullptr, n);
  k_gemm<128,256,true,false><<<(n+63)/64,256,0,stream>>>((const unsigned short*)AX, W1p, b1, nullptr, H1, n);
  // layer 2: T = dinv .* (H1 @ W2) ; out = dinv .* (A+I-gather of T) + b2
  unsigned int* T = xb;
  k_gemm<256,128,false,true><<<(n+127)/128,256,0,stream>>>(H1, W2p, nullptr, dinv, (unsigned short*)T, n);
  k_agg<true><<<(n+3)/4,256,0,stream>>>(T, rp, csr, dinv, b2, nullptr, (float*)d_out, n);
}

// Round 3
// 287.817 us; speedup vs baseline: 2.0256x; 1.4352x over previous
//
#include <hip/hip_runtime.h>

typedef __bf16 bf16x8 __attribute__((ext_vector_type(8)));
typedef float f32x4 __attribute__((ext_vector_type(4)));

#define DEVI static __device__ __forceinline__
#define CHUNK 8192

DEVI unsigned short f2bf(float f){
  unsigned int x = __builtin_bit_cast(unsigned int, f);
  x = (x + 0x7fffu + ((x >> 16) & 1u)) >> 16;
  return (unsigned short)x;
}
DEVI unsigned int packbf2(float a, float b){
  return (unsigned int)f2bf(a) | ((unsigned int)f2bf(b) << 16);
}
DEVI float bflo(unsigned int u){ return __builtin_bit_cast(float, u << 16); }
DEVI float bfhi(unsigned int u){ return __builtin_bit_cast(float, u & 0xffff0000u); }

__global__ void k_zero(int* __restrict__ p, int n){
  int i = blockIdx.x*256 + threadIdx.x;
  if (i < n) p[i] = 0;
}

// ---- bucketed CSR build (bucket = 256 consecutive dst nodes) ----

__global__ __launch_bounds__(256) void kb_hist(const int* __restrict__ dst,
    int* __restrict__ bucketCnt, int E, int NB){
  __shared__ int h[2048];
  for (int i=threadIdx.x;i<NB;i+=256) h[i]=0;
  __syncthreads();
  int base = blockIdx.x*CHUNK;
  int lim = base+CHUNK < E ? base+CHUNK : E;
  for (int i = base+threadIdx.x; i < lim; i += 256)
    atomicAdd(&h[dst[i]>>8], 1);
  __syncthreads();
  for (int i=threadIdx.x;i<NB;i+=256)
    if (h[i]) atomicAdd(&bucketCnt[i], h[i]);
}

__global__ __launch_bounds__(256) void kb_scan(const int* __restrict__ bucketCnt,
    int* __restrict__ bucketOff, int* __restrict__ bucketCur, int NB){
  __shared__ int sh[256];
  int t = threadIdx.x;
  int per = (NB+255)/256;
  int vals[8];
  int lsum = 0;
  for (int j=0;j<per;j++){
    int i = t*per+j;
    int v = (i<NB) ? bucketCnt[i] : 0;
    vals[j]=v; lsum+=v;
  }
  sh[t]=lsum; __syncthreads();
  for (int off=1; off<256; off<<=1){
    int x = (t>=off) ? sh[t-off] : 0;
    __syncthreads();
    sh[t] += x;
    __syncthreads();
  }
  int run = sh[t]-lsum;
  for (int j=0;j<per;j++){
    int i = t*per+j;
    if (i<NB){ bucketOff[i]=run; bucketCur[i]=run; }
    run += vals[j];
  }
  if (t==255) bucketOff[NB]=run;
}

__global__ __launch_bounds__(256) void kb_scatter(const int* __restrict__ src,
    const int* __restrict__ dst, int* __restrict__ bucketCur,
    int* __restrict__ srcb, int* __restrict__ dstb, int E, int NB){
  __shared__ int h[2048];
  __shared__ int baseSh[2048];
  for (int i=threadIdx.x;i<NB;i+=256) h[i]=0;
  __syncthreads();
  int base = blockIdx.x*CHUNK;
  int lim = base+CHUNK < E ? base+CHUNK : E;
  for (int i = base+threadIdx.x; i < lim; i += 256)
    atomicAdd(&h[dst[i]>>8], 1);
  __syncthreads();
  for (int i=threadIdx.x;i<NB;i+=256){
    int c = h[i];
    baseSh[i] = c ? atomicAdd(&bucketCur[i], c) : 0;
    h[i] = 0;
  }
  __syncthreads();
  for (int i = base+threadIdx.x; i < lim; i += 256){
    int d = dst[i];
    int b = d>>8;
    int r = atomicAdd(&h[b], 1);
    int p = baseSh[b] + r;
    srcb[p] = src[i];
    dstb[p] = d;
  }
}

__global__ __launch_bounds__(256) void kb_cnt(const int* __restrict__ dstb,
    const int* __restrict__ bucketOff, int* __restrict__ cnt, int n){
  __shared__ int c[256];
  c[threadIdx.x]=0; __syncthreads();
  int b = blockIdx.x;
  int s = bucketOff[b], e2 = bucketOff[b+1];
  for (int i=s+threadIdx.x;i<e2;i+=256) atomicAdd(&c[dstb[i]&255], 1);
  __syncthreads();
  int node = b*256 + threadIdx.x;
  if (node < n) cnt[node] = c[threadIdx.x];
}

__global__ __launch_bounds__(256) void kb_fill(const int* __restrict__ srcb,
    const int* __restrict__ dstb, const int* __restrict__ bucketOff,
    const int* __restrict__ rp, int* __restrict__ csr){
  __shared__ int c[256];
  c[threadIdx.x]=0; __syncthreads();
  int b = blockIdx.x;
  int s = bucketOff[b], e2 = bucketOff[b+1];
  for (int i=s+threadIdx.x;i<e2;i+=256){
    int d = dstb[i];
    int r = atomicAdd(&c[d&255], 1);
    csr[rp[d]+r] = srcb[i];
  }
}

// ---- node-count prefix scan (cnt -> rp) ----

__global__ void k_scan1(const int* __restrict__ cnt, int* __restrict__ rp,
                        int* __restrict__ partials, int n){
  __shared__ int sh[256];
  int t = threadIdx.x;
  int base = blockIdx.x*1024 + t*4;
  int v0=0,v1=0,v2=0,v3=0;
  if (base+0 < n) v0 = cnt[base+0];
  if (base+1 < n) v1 = cnt[base+1];
  if (base+2 < n) v2 = cnt[base+2];
  if (base+3 < n) v3 = cnt[base+3];
  int s = v0+v1+v2+v3;
  sh[t] = s; __syncthreads();
  for (int off=1; off<256; off<<=1){
    int x = (t>=off) ? sh[t-off] : 0;
    __syncthreads();
    sh[t] += x;
    __syncthreads();
  }
  if (t==255) partials[blockIdx.x] = sh[255];
  int run = sh[t]-s;
  if (base+0 < n) rp[base+0] = run; run += v0;
  if (base+1 < n) rp[base+1] = run; run += v1;
  if (base+2 < n) rp[base+2] = run; run += v2;
  if (base+3 < n) rp[base+3] = run;
}

__global__ void k_scan2(int* __restrict__ partials, int P){
  __shared__ int sh[256];
  int t = threadIdx.x;
  int v = (t<P) ? partials[t] : 0;
  sh[t] = v; __syncthreads();
  for (int off=1; off<256; off<<=1){
    int x = (t>=off) ? sh[t-off] : 0;
    __syncthreads();
    sh[t] += x;
    __syncthreads();
  }
  if (t<P) partials[t] = sh[t]-v;
}

__global__ void k_scan3(int* __restrict__ rp, const int* __restrict__ partials,
                        int n, int E){
  int i = blockIdx.x*256 + threadIdx.x;
  if (i < n) rp[i] += partials[i>>10];
  else if (i == n) rp[n] = E;
}

__global__ void k_dinv(const int* __restrict__ cnt, float* __restrict__ dinv, int n){
  int i = blockIdx.x*256 + threadIdx.x;
  if (i<n) dinv[i] = rsqrtf((float)(cnt[i]+1));
}

// xs[node] = bf16(dinv[node] * x[node])  (pre-scaled rows)
__global__ void k_cvt(const float2* __restrict__ x, const float* __restrict__ dinv,
                      unsigned int* __restrict__ xb, int n2){
  int i = blockIdx.x*256 + threadIdx.x;
  if (i<n2){
    float d = dinv[i>>6];
    float2 v = x[i];
    xb[i] = packbf2(d*v.x, d*v.y);
  }
}

// Pack row-major fp32 W[K][N] into MFMA B-fragment order:
// frag (ks, cf), lane l, elem j  <-  W[ks*32 + (l>>4)*8 + j][cf*16 + (l&15)]
__global__ void k_pack(const float* __restrict__ W, unsigned short* __restrict__ Wp,
                       int N, int KS, int NF){
  int idx = blockIdx.x*256 + threadIdx.x;
  if (idx >= KS*NF*64) return;
  int l = idx & 63;
  int frag = idx >> 6;
  int cf = frag % NF;
  int ks = frag / NF;
  int kbase = ks*32 + (l>>4)*8;
  int col = cf*16 + (l&15);
  unsigned short* dp = Wp + (size_t)idx*8;
  for (int j=0;j<8;j++) dp[j] = f2bf(W[(size_t)(kbase+j)*N + col]);
}

// Aggregate pre-scaled rows: out[d] = dinv[d] * (sum_{s in N(d)} xs[s] + xs[d])
// One wave per node, lane l owns feature pair {2l,2l+1} (4B). 8-wide unrolled
// gather loop for MLP; predicated tail (clamped index, zeroed value).
template<bool FINAL>
__global__ __launch_bounds__(256) void k_agg(
    const unsigned int* __restrict__ xs, const int* __restrict__ rp,
    const int* __restrict__ csr, const float* __restrict__ dinv,
    const float* __restrict__ bias, unsigned int* __restrict__ outb,
    float* __restrict__ outf, int n){
  int node = blockIdx.x*4 + (threadIdx.x>>6);
  if (node >= n) return;
  int l = threadIdx.x & 63;
  float dn = dinv[node];
  unsigned int u = xs[(size_t)node*64 + l];
  float a0 = bflo(u), a1 = bfhi(u);
  int e = rp[node], end = rp[node+1];
  for (int base = e; base < end; base += 8){
    int idx[8];
    unsigned int v[8];
    #pragma unroll
    for (int i=0;i<8;i++){
      int ei = base+i < end-1 ? base+i : end-1;
      idx[i] = csr[ei];
    }
    #pragma unroll
    for (int i=0;i<8;i++)
      v[i] = xs[(size_t)idx[i]*64 + l];
    #pragma unroll
    for (int i=0;i<8;i++){
      if (base+i >= end) v[i] = 0;
      a0 += bflo(v[i]);
      a1 += bfhi(v[i]);
    }
  }
  if constexpr (FINAL){
    float2 r;
    r.x = a0*dn + bias[2*l];
    r.y = a1*dn + bias[2*l+1];
    *(float2*)(outf + (size_t)node*128 + 2*l) = r;
  } else {
    outb[(size_t)node*64 + l] = packbf2(a0*dn, a1*dn);
  }
}

// C[M][N] (bf16) = A[M][K] (bf16, row-major) @ Wp (packed frags)
// [+bias+relu] or [*rowscale] epilogue.
// 4 waves/block; wave computes 64x64 via 4x4 grid of 16x16x32 MFMA fragments.
template<int K, int N, bool BIASRELU, bool ROWSCALE>
__global__ __launch_bounds__(256) void k_gemm(
    const unsigned short* __restrict__ A, const unsigned short* __restrict__ Wp,
    const float* __restrict__ bias, const float* __restrict__ rowscale,
    unsigned short* __restrict__ C, int M){
  constexpr int KS = K/32;
  constexpr int NF = N/16;
  constexpr int NWC = N/64;       // waves along cols
  constexpr int NWR = 4/NWC;      // waves along rows
  constexpr int BM = 64*NWR;
  int l = threadIdx.x & 63;
  int w = threadIdx.x >> 6;
  int wr = w / NWC, wc = w % NWC;
  int r0 = blockIdx.x*BM + wr*64;
  int c0 = wc*64;
  int lr = l & 15, lg = l >> 4;
  f32x4 acc[4][4];
  #pragma unroll
  for (int i=0;i<4;i++)
    #pragma unroll
    for (int j=0;j<4;j++)
      acc[i][j] = f32x4{0.f,0.f,0.f,0.f};
  for (int ks=0; ks<KS; ++ks){
    bf16x8 a[4], b[4];
    #pragma unroll
    for (int ar=0;ar<4;ar++){
      int row = r0 + ar*16 + lr;
      if (row > M-1) row = M-1;
      const uint4* p = (const uint4*)(A + (size_t)row*K + ks*32 + lg*8);
      union { uint4 u; bf16x8 v; } t; t.u = *p; a[ar] = t.v;
    }
    #pragma unroll
    for (int cb=0;cb<4;cb++){
      int cf = (c0>>4) + cb;
      const uint4* p = (const uint4*)(Wp + ((size_t)(ks*NF + cf)*64 + l)*8);
      union { uint4 u; bf16x8 v; } t; t.u = *p; b[cb] = t.v;
    }
    #pragma unroll
    for (int ar=0;ar<4;ar++)
      #pragma unroll
      for (int cb=0;cb<4;cb++)
        acc[ar][cb] = __builtin_amdgcn_mfma_f32_16x16x32_bf16(a[ar], b[cb], acc[ar][cb], 0, 0, 0);
  }
  #pragma unroll
  for (int ar=0;ar<4;ar++){
    #pragma unroll
    for (int i=0;i<4;i++){
      int row = r0 + ar*16 + lg*4 + i;
      if (row < M){
        float rs = 1.f;
        if constexpr (ROWSCALE) rs = rowscale[row];
        #pragma unroll
        for (int cb=0;cb<4;cb++){
          int col = c0 + cb*16 + lr;
          float v = acc[ar][cb][i];
          if constexpr (BIASRELU){ v += bias[col]; v = fmaxf(v, 0.f); }
          if constexpr (ROWSCALE) v *= rs;
          C[(size_t)row*N + col] = f2bf(v);
        }
      }
    }
  }
}

extern "C" void kernel_launch(void* const* d_in, const int* in_sizes, int n_in,
                              void* d_out, int out_size, void* d_ws, size_t ws_size,
                              hipStream_t stream){
  const float* x  = (const float*)d_in[0];
  const int*   ei = (const int*)d_in[1];
  const float* W1 = (const float*)d_in[2];
  const float* b1 = (const float*)d_in[3];
  const float* W2 = (const float*)d_in[4];
  const float* b2 = (const float*)d_in[5];
  const int IN_F = 128, H_F = 256, OUT_F = 128;
  int n = in_sizes[0] / IN_F;      // 100000
  int E = in_sizes[1] / 2;         // 1600000
  const int* srcI = ei;
  const int* dstI = ei + E;
  const int NB = (n+255)>>8;       // buckets of 256 nodes

  char* ws = (char*)d_ws;
  size_t off = 0;
  auto alloc = [&](size_t bytes)->char*{
    char* p = ws + off; off += (bytes + 255) & ~(size_t)255; return p;
  };
  int*   cnt   = (int*)  alloc((size_t)n*4);
  int*   rp    = (int*)  alloc(((size_t)n+1)*4);
  float* dinv  = (float*)alloc((size_t)n*4);
  int*   parts = (int*)  alloc(1024);
  int*   bCnt  = (int*)  alloc((size_t)NB*4);
  int*   bOff  = (int*)  alloc(((size_t)NB+1)*4);
  int*   bCur  = (int*)  alloc((size_t)NB*4);
  unsigned short* W1p = (unsigned short*)alloc((size_t)IN_F*H_F*2);
  unsigned short* W2p = (unsigned short*)alloc((size_t)H_F*OUT_F*2);
  int*   csr   = (int*)  alloc((size_t)E*4);
  unsigned int* xb = (unsigned int*)alloc((size_t)n*(IN_F/2)*4);  // reused as T after GEMM1
  unsigned int* AX = (unsigned int*)alloc((size_t)n*(IN_F/2)*4);
  unsigned short* H1 = (unsigned short*)alloc((size_t)n*H_F*2);
  // bucketed edge pairs alias H1 (dead before GEMM1 writes H1)
  int* srcb = (int*)H1;
  int* dstb = srcb + E;

  int g256n = (n+255)/256;
  int P = (n+1023)/1024;
  int NCH = (E + CHUNK - 1)/CHUNK;

  k_zero<<<(NB+255)/256,256,0,stream>>>(bCnt, NB);
  kb_hist<<<NCH,256,0,stream>>>(dstI, bCnt, E, NB);
  kb_scan<<<1,256,0,stream>>>(bCnt, bOff, bCur, NB);
  kb_scatter<<<NCH,256,0,stream>>>(srcI, dstI, bCur, srcb, dstb, E, NB);
  kb_cnt<<<NB,256,0,stream>>>(dstb, bOff, cnt, n);
  k_scan1<<<P,256,0,stream>>>(cnt, rp, parts, n);
  k_scan2<<<1,256,0,stream>>>(parts, P);
  k_scan3<<<(n+256)/256,256,0,stream>>>(rp, parts, n, E);
  k_dinv<<<g256n,256,0,stream>>>(cnt, dinv, n);
  k_cvt<<<((n*(IN_F/2))+255)/256,256,0,stream>>>((const float2*)x, dinv, xb, n*(IN_F/2));
  k_pack<<<16,256,0,stream>>>(W1, W1p, H_F, IN_F/32, H_F/16);
  k_pack<<<16,256,0,stream>>>(W2, W2p, OUT_F, H_F/32, OUT_F/16);
  kb_fill<<<NB,256,0,stream>>>(srcb, dstb, bOff, rp, csr);
  // layer 1: AX = A_hat @ xs ; H1 = relu(AX @ W1 + b1)
  k_agg<false><<<(n+3)/4,256,0,stream>>>(xb, rp, csr, dinv, nullptr, AX, nullptr, n);
  k_gemm<128,256,true,false><<<(n+63)/64,256,0,stream>>>((const unsigned short*)AX, W1p, b1, nullptr, H1, n);
  // layer 2: T = dinv .* (H1 @ W2) ; out = dinv .* (A+I-gather of T) + b2
  unsigned int* T = xb;
  k_gemm<256,128,false,true><<<(n+127)/128,256,0,stream>>>(H1, W2p, nullptr, dinv, (unsigned short*)T, n);
  k_agg<true><<<(n+3)/4,256,0,stream>>>(T, rp, csr, dinv, b2, nullptr, (float*)d_out, n);
}

// Round 4
// 282.065 us; speedup vs baseline: 2.0669x; 1.0204x over previous
//
#include <hip/hip_runtime.h>

typedef __bf16 bf16x8 __attribute__((ext_vector_type(8)));
typedef float f32x4 __attribute__((ext_vector_type(4)));

#define DEVI static __device__ __forceinline__
#define CHUNK 4096

DEVI unsigned short f2bf(float f){
  unsigned int x = __builtin_bit_cast(unsigned int, f);
  x = (x + 0x7fffu + ((x >> 16) & 1u)) >> 16;
  return (unsigned short)x;
}
DEVI unsigned int packbf2(float a, float b){
  return (unsigned int)f2bf(a) | ((unsigned int)f2bf(b) << 16);
}
DEVI float bflo(unsigned int u){ return __builtin_bit_cast(float, u << 16); }
DEVI float bfhi(unsigned int u){ return __builtin_bit_cast(float, u & 0xffff0000u); }

__global__ void k_zero(int* __restrict__ p, int n){
  int i = blockIdx.x*256 + threadIdx.x;
  if (i < n) p[i] = 0;
}

// ---- bucketed CSR build (bucket = 256 consecutive dst nodes) ----

__global__ __launch_bounds__(256) void kb_hist(const int* __restrict__ dst,
    int* __restrict__ bucketCnt, int E, int NB){
  __shared__ int h[2048];
  for (int i=threadIdx.x;i<NB;i+=256) h[i]=0;
  __syncthreads();
  int base = blockIdx.x*CHUNK;
  int lim = base+CHUNK < E ? base+CHUNK : E;
  for (int i = base+threadIdx.x; i < lim; i += 256)
    atomicAdd(&h[dst[i]>>8], 1);
  __syncthreads();
  for (int i=threadIdx.x;i<NB;i+=256)
    if (h[i]) atomicAdd(&bucketCnt[i], h[i]);
}

__global__ __launch_bounds__(256) void kb_scan(const int* __restrict__ bucketCnt,
    int* __restrict__ bucketOff, int* __restrict__ bucketCur, int NB){
  __shared__ int sh[256];
  int t = threadIdx.x;
  int per = (NB+255)/256;
  int vals[8];
  int lsum = 0;
  for (int j=0;j<per;j++){
    int i = t*per+j;
    int v = (i<NB) ? bucketCnt[i] : 0;
    vals[j]=v; lsum+=v;
  }
  sh[t]=lsum; __syncthreads();
  for (int off=1; off<256; off<<=1){
    int x = (t>=off) ? sh[t-off] : 0;
    __syncthreads();
    sh[t] += x;
    __syncthreads();
  }
  int run = sh[t]-lsum;
  for (int j=0;j<per;j++){
    int i = t*per+j;
    if (i<NB){ bucketOff[i]=run; bucketCur[i]=run; }
    run += vals[j];
  }
  if (t==255) bucketOff[NB]=run;
}

__global__ __launch_bounds__(256) void kb_scatter(const int* __restrict__ src,
    const int* __restrict__ dst, int* __restrict__ bucketCur,
    int* __restrict__ srcb, int* __restrict__ dstb, int E, int NB){
  __shared__ int h[2048];
  __shared__ int baseSh[2048];
  for (int i=threadIdx.x;i<NB;i+=256) h[i]=0;
  __syncthreads();
  int base = blockIdx.x*CHUNK;
  int lim = base+CHUNK < E ? base+CHUNK : E;
  for (int i = base+threadIdx.x; i < lim; i += 256)
    atomicAdd(&h[dst[i]>>8], 1);
  __syncthreads();
  for (int i=threadIdx.x;i<NB;i+=256){
    int c = h[i];
    baseSh[i] = c ? atomicAdd(&bucketCur[i], c) : 0;
    h[i] = 0;
  }
  __syncthreads();
  for (int i = base+threadIdx.x; i < lim; i += 256){
    int d = dst[i];
    int b = d>>8;
    int r = atomicAdd(&h[b], 1);
    int p = baseSh[b] + r;
    srcb[p] = src[i];
    dstb[p] = d;
  }
}

// Fused per-bucket: count per node -> LDS scan -> rp/dinv -> rank & write csr.
// csr entries are pre-shifted BYTE offsets (src*256).
__global__ __launch_bounds__(256) void kb_fused(const int* __restrict__ srcb,
    const int* __restrict__ dstb, const int* __restrict__ bOff,
    int* __restrict__ rp, int* __restrict__ csr, float* __restrict__ dinv,
    int n, int NB, int E){
  __shared__ int c[256];
  __shared__ int sh[256];
  __shared__ int cur[256];
  int t = threadIdx.x;
  int b = blockIdx.x;
  int s = bOff[b], e2 = bOff[b+1];
  c[t]=0; __syncthreads();
  for (int i=s+t;i<e2;i+=256) atomicAdd(&c[dstb[i]&255], 1);
  __syncthreads();
  int deg = c[t];
  sh[t]=deg; __syncthreads();
  for (int o=1;o<256;o<<=1){
    int x = (t>=o) ? sh[t-o] : 0;
    __syncthreads();
    sh[t]+=x;
    __syncthreads();
  }
  int excl = sh[t]-deg;
  int node = b*256+t;
  if (node<n){
    rp[node] = s + excl;
    dinv[node] = rsqrtf((float)(deg+1));
  }
  if (b==NB-1 && t==0) rp[n] = E;
  cur[t] = s + excl;
  __syncthreads();
  for (int i=s+t;i<e2;i+=256){
    int d = dstb[i]&255;
    int r = atomicAdd(&cur[d], 1);
    csr[r] = srcb[i] << 8;
  }
}

// xs[node] = bf16(dinv[node] * x[node])  (pre-scaled rows)
__global__ void k_cvt(const float2* __restrict__ x, const float* __restrict__ dinv,
                      unsigned int* __restrict__ xb, int n2){
  int i = blockIdx.x*256 + threadIdx.x;
  if (i<n2){
    float d = dinv[i>>6];
    float2 v = x[i];
    xb[i] = packbf2(d*v.x, d*v.y);
  }
}

// Pack row-major fp32 W[K][N] into MFMA B-fragment order:
// frag (ks, cf), lane l, elem j  <-  W[ks*32 + (l>>4)*8 + j][cf*16 + (l&15)]
DEVI void packW(const float* __restrict__ W, unsigned short* __restrict__ Wp,
                int idx, int N, int NF){
  int l = idx & 63;
  int frag = idx >> 6;
  int cf = frag % NF;
  int ks = frag / NF;
  int kbase = ks*32 + (l>>4)*8;
  int col = cf*16 + (l&15);
  unsigned short* dp = Wp + (size_t)idx*8;
  #pragma unroll
  for (int j=0;j<8;j++) dp[j] = f2bf(W[(size_t)(kbase+j)*N + col]);
}

__global__ void k_pack2(const float* __restrict__ W1, unsigned short* __restrict__ W1p,
                        const float* __restrict__ W2, unsigned short* __restrict__ W2p){
  int idx = blockIdx.x*256 + threadIdx.x;
  if (idx < 4096) packW(W1, W1p, idx, 256, 16);        // K=128,N=256: 4*16*64
  else            packW(W2, W2p, idx-4096, 128, 8);    // K=256,N=128: 8*8*64
}

// Aggregate pre-scaled rows: out[d] = dinv[d] * (sum_{s in N(d)} xs[s] + xs[d])
// One wave per node. Lane l: quarter h=l>>4 handles edge sub-slot h, q=l&15
// owns features [8q, 8q+8) (16B uint4). Each gather instr covers 4 edges x 16B.
// Quarter partials reduced via shfl_xor(16/32). csr holds byte offsets.
#define ACC8(V) { a0+=bflo(V.x); a1+=bfhi(V.x); a2+=bflo(V.y); a3+=bfhi(V.y); \
                  a4+=bflo(V.z); a5+=bfhi(V.z); a6+=bflo(V.w); a7+=bfhi(V.w); }

template<bool FINAL>
__global__ __launch_bounds__(256) void k_agg(
    const unsigned int* __restrict__ xs, const int* __restrict__ rp,
    const int* __restrict__ csr, const float* __restrict__ dinv,
    const float* __restrict__ bias, unsigned int* __restrict__ outb,
    float* __restrict__ outf, int n){
  int node = blockIdx.x*4 + (threadIdx.x>>6);
  if (node >= n) return;
  int l = threadIdx.x & 63;
  int q = l & 15;
  int h = l >> 4;
  const char* xbase = (const char*)xs;
  float a0=0,a1=0,a2=0,a3=0,a4=0,a5=0,a6=0,a7=0;
  int e = rp[node], end = rp[node+1];
  int p = e;
  int nf = (end - e) >> 4;
  for (int blk=0; blk<nf; ++blk, p+=16){
    uint4 v[4];
    #pragma unroll
    for (int i=0;i<4;i++){
      int boff = csr[p + 4*i + h];
      v[i] = *(const uint4*)(xbase + (size_t)(unsigned)boff + q*16);
    }
    ACC8(v[0]); ACC8(v[1]); ACC8(v[2]); ACC8(v[3]);
  }
  int rem = end - p;
  if (rem >= 8){
    uint4 v[2];
    #pragma unroll
    for (int i=0;i<2;i++){
      int boff = csr[p + 4*i + h];
      v[i] = *(const uint4*)(xbase + (size_t)(unsigned)boff + q*16);
    }
    ACC8(v[0]); ACC8(v[1]);
    p += 8; rem -= 8;
  }
  if (rem > 0){
    uint4 v[2];
    #pragma unroll
    for (int i=0;i<2;i++){
      int ei = p + 4*i + h;
      int ec = ei < end-1 ? ei : end-1;
      int boff = csr[ec];
      uint4 t = *(const uint4*)(xbase + (size_t)(unsigned)boff + q*16);
      if (ei >= end){ t.x=0; t.y=0; t.z=0; t.w=0; }
      v[i] = t;
    }
    ACC8(v[0]); ACC8(v[1]);
  }
  a0 += __shfl_xor(a0,16); a0 += __shfl_xor(a0,32);
  a1 += __shfl_xor(a1,16); a1 += __shfl_xor(a1,32);
  a2 += __shfl_xor(a2,16); a2 += __shfl_xor(a2,32);
  a3 += __shfl_xor(a3,16); a3 += __shfl_xor(a3,32);
  a4 += __shfl_xor(a4,16); a4 += __shfl_xor(a4,32);
  a5 += __shfl_xor(a5,16); a5 += __shfl_xor(a5,32);
  a6 += __shfl_xor(a6,16); a6 += __shfl_xor(a6,32);
  a7 += __shfl_xor(a7,16); a7 += __shfl_xor(a7,32);
  // self term
  uint4 sv = *(const uint4*)(xbase + (size_t)node*256 + q*16);
  ACC8(sv);
  float dn = dinv[node];
  if constexpr (FINAL){
    if (h < 2){
      const float4 bb = *(const float4*)(bias + 8*q + 4*h);
      float4 r;
      r.x = (h ? a4 : a0)*dn + bb.x;
      r.y = (h ? a5 : a1)*dn + bb.y;
      r.z = (h ? a6 : a2)*dn + bb.z;
      r.w = (h ? a7 : a3)*dn + bb.w;
      *(float4*)(outf + (size_t)node*128 + 8*q + 4*h) = r;
    }
  } else {
    if (h == 0){
      uint4 o;
      o.x = packbf2(a0*dn, a1*dn);
      o.y = packbf2(a2*dn, a3*dn);
      o.z = packbf2(a4*dn, a5*dn);
      o.w = packbf2(a6*dn, a7*dn);
      *(uint4*)((char*)outb + (size_t)node*256 + q*16) = o;
    }
  }
}

// C[M][N] (bf16) = A[M][K] (bf16, row-major) @ Wp (packed frags)
// [+bias+relu] or [*rowscale] epilogue.
// 4 waves/block; wave computes 64x64 via 4x4 grid of 16x16x32 MFMA fragments.
template<int K, int N, bool BIASRELU, bool ROWSCALE>
__global__ __launch_bounds__(256) void k_gemm(
    const unsigned short* __restrict__ A, const unsigned short* __restrict__ Wp,
    const float* __restrict__ bias, const float* __restrict__ rowscale,
    unsigned short* __restrict__ C, int M){
  constexpr int KS = K/32;
  constexpr int NF = N/16;
  constexpr int NWC = N/64;       // waves along cols
  constexpr int NWR = 4/NWC;      // waves along rows
  constexpr int BM = 64*NWR;
  int l = threadIdx.x & 63;
  int w = threadIdx.x >> 6;
  int wr = w / NWC, wc = w % NWC;
  int r0 = blockIdx.x*BM + wr*64;
  int c0 = wc*64;
  int lr = l & 15, lg = l >> 4;
  f32x4 acc[4][4];
  #pragma unroll
  for (int i=0;i<4;i++)
    #pragma unroll
    for (int j=0;j<4;j++)
      acc[i][j] = f32x4{0.f,0.f,0.f,0.f};
  for (int ks=0; ks<KS; ++ks){
    bf16x8 a[4], b[4];
    #pragma unroll
    for (int ar=0;ar<4;ar++){
      int row = r0 + ar*16 + lr;
      if (row > M-1) row = M-1;
      const uint4* p = (const uint4*)(A + (size_t)row*K + ks*32 + lg*8);
      union { uint4 u; bf16x8 v; } t; t.u = *p; a[ar] = t.v;
    }
    #pragma unroll
    for (int cb=0;cb<4;cb++){
      int cf = (c0>>4) + cb;
      const uint4* p = (const uint4*)(Wp + ((size_t)(ks*NF + cf)*64 + l)*8);
      union { uint4 u; bf16x8 v; } t; t.u = *p; b[cb] = t.v;
    }
    #pragma unroll
    for (int ar=0;ar<4;ar++)
      #pragma unroll
      for (int cb=0;cb<4;cb++)
        acc[ar][cb] = __builtin_amdgcn_mfma_f32_16x16x32_bf16(a[ar], b[cb], acc[ar][cb], 0, 0, 0);
  }
  #pragma unroll
  for (int ar=0;ar<4;ar++){
    #pragma unroll
    for (int i=0;i<4;i++){
      int row = r0 + ar*16 + lg*4 + i;
      if (row < M){
        float rs = 1.f;
        if constexpr (ROWSCALE) rs = rowscale[row];
        #pragma unroll
        for (int cb=0;cb<4;cb++){
          int col = c0 + cb*16 + lr;
          float v = acc[ar][cb][i];
          if constexpr (BIASRELU){ v += bias[col]; v = fmaxf(v, 0.f); }
          if constexpr (ROWSCALE) v *= rs;
          C[(size_t)row*N + col] = f2bf(v);
        }
      }
    }
  }
}

extern "C" void kernel_launch(void* const* d_in, const int* in_sizes, int n_in,
                              void* d_out, int out_size, void* d_ws, size_t ws_size,
                              hipStream_t stream){
  const float* x  = (const float*)d_in[0];
  const int*   ei = (const int*)d_in[1];
  const float* W1 = (const float*)d_in[2];
  const float* b1 = (const float*)d_in[3];
  const float* W2 = (const float*)d_in[4];
  const float* b2 = (const float*)d_in[5];
  const int IN_F = 128, H_F = 256, OUT_F = 128;
  int n = in_sizes[0] / IN_F;      // 100000
  int E = in_sizes[1] / 2;         // 1600000
  const int* srcI = ei;
  const int* dstI = ei + E;
  const int NB = (n+255)>>8;       // buckets of 256 nodes

  char* ws = (char*)d_ws;
  size_t off = 0;
  auto alloc = [&](size_t bytes)->char*{
    char* p = ws + off; off += (bytes + 255) & ~(size_t)255; return p;
  };
  int*   rp    = (int*)  alloc(((size_t)n+1)*4);
  float* dinv  = (float*)alloc((size_t)n*4);
  int*   bCnt  = (int*)  alloc((size_t)NB*4);
  int*   bOff  = (int*)  alloc(((size_t)NB+1)*4);
  int*   bCur  = (int*)  alloc((size_t)NB*4);
  unsigned short* W1p = (unsigned short*)alloc((size_t)IN_F*H_F*2);
  unsigned short* W2p = (unsigned short*)alloc((size_t)H_F*OUT_F*2);
  int*   csr   = (int*)  alloc((size_t)E*4);
  unsigned int* xb = (unsigned int*)alloc((size_t)n*(IN_F/2)*4);  // reused as T after GEMM1
  unsigned int* AX = (unsigned int*)alloc((size_t)n*(IN_F/2)*4);
  unsigned short* H1 = (unsigned short*)alloc((size_t)n*H_F*2);
  // bucketed edge pairs alias H1 (dead before GEMM1 writes H1)
  int* srcb = (int*)H1;
  int* dstb = srcb + E;

  int NCH = (E + CHUNK - 1)/CHUNK;

  k_zero<<<(NB+255)/256,256,0,stream>>>(bCnt, NB);
  kb_hist<<<NCH,256,0,stream>>>(dstI, bCnt, E, NB);
  kb_scan<<<1,256,0,stream>>>(bCnt, bOff, bCur, NB);
  kb_scatter<<<NCH,256,0,stream>>>(srcI, dstI, bCur, srcb, dstb, E, NB);
  kb_fused<<<NB,256,0,stream>>>(srcb, dstb, bOff, rp, csr, dinv, n, NB, E);
  k_cvt<<<((n*(IN_F/2))+255)/256,256,0,stream>>>((const float2*)x, dinv, xb, n*(IN_F/2));
  k_pack2<<<32,256,0,stream>>>(W1, W1p, W2, W2p);
  // layer 1: AX = A_hat @ xs ; H1 = relu(AX @ W1 + b1)
  k_agg<false><<<(n+3)/4,256,0,stream>>>(xb, rp, csr, dinv, nullptr, AX, nullptr, n);
  k_gemm<128,256,true,false><<<(n+63)/64,256,0,stream>>>((const unsigned short*)AX, W1p, b1, nullptr, H1, n);
  // layer 2: T = dinv .* (H1 @ W2) ; out = dinv .* (A+I-gather of T) + b2
  unsigned int* T = xb;
  k_gemm<256,128,false,true><<<(n+127)/128,256,0,stream>>>(H1, W2p, nullptr, dinv, (unsigned short*)T, n);
  k_agg<true><<<(n+3)/4,256,0,stream>>>(T, rp, csr, dinv, b2, nullptr, (float*)d_out, n);
}